// Round 7
// baseline (65.986 us; speedup 1.0000x reference)
//
#include <hip/hip_runtime.h>
#include <math.h>

constexpr float INV_B = 1.0f / 16384.0f;
constexpr float BN_EPS_C = 1e-5f;
constexpr int NUM_USERS_C = 1000000;
#define NBLK 256

typedef __attribute__((ext_vector_type(8))) short bf16x8;
typedef __attribute__((ext_vector_type(4))) float f32x4;

__device__ inline unsigned short f2bf(float f) {
    union { float f; unsigned u; } v; v.f = f;
    unsigned r = v.u + 0x7FFFu + ((v.u >> 16) & 1u);   // RNE
    return (unsigned short)(r >> 16);
}
__device__ inline float bf2f(unsigned short h) {
    union { unsigned u; float f; } v; v.u = ((unsigned)h) << 16; return v.f;
}
__device__ inline bf16x8 pack8(float4 a, float4 b) {
    bf16x8 sv;
    sv[0] = (short)f2bf(a.x); sv[1] = (short)f2bf(a.y);
    sv[2] = (short)f2bf(a.z); sv[3] = (short)f2bf(a.w);
    sv[4] = (short)f2bf(b.x); sv[5] = (short)f2bf(b.y);
    sv[6] = (short)f2bf(b.z); sv[7] = (short)f2bf(b.w);
    return sv;
}
// XOR swizzles for pitch-256B / pitch-512B row-major bf16 LDS tiles
__device__ inline unsigned swz256(int r, int kb) { return (unsigned)(r * 256 + (kb ^ ((r & 7) << 4))); }
__device__ inline unsigned swz512(int r, int kb) { return (unsigned)(r * 512 + (kb ^ ((r & 7) << 4))); }

// device-scope spin barrier; safe because all NBLK blocks are co-resident
__device__ inline void gbar(int* cnt) {
    __syncthreads();
    if (threadIdx.x == 0) {
        __threadfence();   // release prior global writes/atomics
        __hip_atomic_fetch_add(cnt, 1, __ATOMIC_ACQ_REL, __HIP_MEMORY_SCOPE_AGENT);
        while (__hip_atomic_load(cnt, __ATOMIC_ACQUIRE, __HIP_MEMORY_SCOPE_AGENT) < NBLK)
            __builtin_amdgcn_s_sleep(8);
    }
    __syncthreads();
}

// ---------------------------------------------------------------------------
// Fully fused Wide&Deep. 256 blocks x 512 threads x 64 rows.
// h1 in LDS (BN1 in place); h2 in registers across barrier 2.
// Cross-block state (part1/part2/counters) touched ONLY via device atomics.
// ---------------------------------------------------------------------------
__global__ __launch_bounds__(512, 2) void wd_fused(
    const int* __restrict__ ui, const int* __restrict__ ii,
    const float* __restrict__ wide_w, const float* __restrict__ wide_b,
    const float* __restrict__ utab, const float* __restrict__ itab,
    const float* __restrict__ W1, const float* __restrict__ b1,
    const float* __restrict__ g1, const float* __restrict__ be1,
    const float* __restrict__ W2, const float* __restrict__ b2,
    const float* __restrict__ g2, const float* __restrict__ be2,
    const float* __restrict__ W3, const float* __restrict__ b3,
    float* __restrict__ part1, float* __restrict__ part2,
    int* __restrict__ cnt1, int* __restrict__ cnt2,
    float* __restrict__ out)
{
    __shared__ char Xs[16384];       // X tile: 64 r x 256B, swizzled
    __shared__ char Hs[32768];       // h1 tile: 64 r x 512B, swizzled
    __shared__ float sstat[512];
    __shared__ float a1s[256], c1s[256];
    __shared__ float af[128], cf[128];
    __shared__ float red[512];
    __shared__ float wide_s[64];
    __shared__ float C2s;

    const int tid = threadIdx.x, bid = blockIdx.x, row0 = bid * 64;
    const int w = tid >> 6, lane = tid & 63, lr = lane & 15, lk = lane >> 4;
    const int mh = w >> 2, nq = w & 3;        // layer-1 wave tile: rows mh*32, cols nq*64

    sstat[tid] = 0.f;

    // wide-path prefetch
    if (tid < 64)
        wide_s[tid] = wide_w[ui[row0 + tid]] + wide_w[NUM_USERS_C + ii[row0 + tid]];

    // stage X: gather + convert (64 rows x 16 chunks)
#pragma unroll
    for (int it = 0; it < 2; ++it) {
        int idx = it * 512 + tid, row = idx >> 4, kc = idx & 15;
        const float* src = (kc < 8)
            ? utab + (size_t)ui[row0 + row] * 64 + kc * 8
            : itab + (size_t)ii[row0 + row] * 64 + (kc - 8) * 8;
        float4 a = ((const float4*)src)[0];
        float4 b = ((const float4*)src)[1];
        *(bf16x8*)(Xs + swz256(row, kc * 16)) = pack8(a, b);
    }

    // inline-convert W1 fragments for this wave's 64 cols (L2-resident)
    bf16x8 b1f[4][4];
#pragma unroll
    for (int nj = 0; nj < 4; ++nj) {
        int n = nq * 64 + nj * 16 + lr;
        const float* wp = W1 + (size_t)n * 128 + lk * 8;
#pragma unroll
        for (int kst = 0; kst < 4; ++kst) {
            float4 va = ((const float4*)(wp + kst * 32))[0];
            float4 vb = ((const float4*)(wp + kst * 32))[1];
            b1f[nj][kst] = pack8(va, vb);
        }
    }
    __syncthreads();

    // ---- layer 1: M=64 N=256 K=128 ----
    f32x4 acc1[2][4];
#pragma unroll
    for (int mi = 0; mi < 2; ++mi)
#pragma unroll
        for (int nj = 0; nj < 4; ++nj) acc1[mi][nj] = (f32x4){0.f, 0.f, 0.f, 0.f};
#pragma unroll
    for (int kst = 0; kst < 4; ++kst) {
        int kb = kst * 64 + lk * 16;
        bf16x8 a0 = *(const bf16x8*)(Xs + swz256(mh * 32 + lr, kb));
        bf16x8 a1 = *(const bf16x8*)(Xs + swz256(mh * 32 + 16 + lr, kb));
#pragma unroll
        for (int nj = 0; nj < 4; ++nj) {
            acc1[0][nj] = __builtin_amdgcn_mfma_f32_16x16x32_bf16(a0, b1f[nj][kst], acc1[0][nj], 0, 0, 0);
            acc1[1][nj] = __builtin_amdgcn_mfma_f32_16x16x32_bf16(a1, b1f[nj][kst], acc1[1][nj], 0, 0, 0);
        }
    }

    // inline-convert W2 fragments for this lane's layer-2 column (hidden under epilogue)
    const int n2 = w * 16 + lr;
    bf16x8 b2f[8];
#pragma unroll
    for (int k8 = 0; k8 < 8; ++k8) {
        const float* wp = W2 + (size_t)n2 * 256 + k8 * 32 + lk * 8;
        float4 va = ((const float4*)wp)[0];
        float4 vb = ((const float4*)wp)[1];
        b2f[k8] = pack8(va, vb);
    }

    // layer-1 epilogue: bias+ReLU+bf16 -> Hs; column stats
#pragma unroll
    for (int nj = 0; nj < 4; ++nj) {
        int col = nq * 64 + nj * 16 + lr;
        float bias = b1[col];
        float s = 0.f, q = 0.f;
#pragma unroll
        for (int mi = 0; mi < 2; ++mi)
#pragma unroll
            for (int reg = 0; reg < 4; ++reg) {
                int rl = mh * 32 + mi * 16 + lk * 4 + reg;
                float v = fmaxf(acc1[mi][nj][reg] + bias, 0.f);
                unsigned short hb = f2bf(v);
                float vr = bf2f(hb);
                s += vr; q += vr * vr;
                *(unsigned short*)(Hs + swz512(rl, col * 2)) = hb;
            }
        s += __shfl_xor(s, 16); s += __shfl_xor(s, 32);
        q += __shfl_xor(q, 16); q += __shfl_xor(q, 32);
        if (lk == 0) { atomicAdd(&sstat[col], s); atomicAdd(&sstat[256 + col], q); }
    }
    __syncthreads();
    atomicAdd(&part1[(size_t)(bid & 7) * 512 + tid], sstat[tid]);

    gbar(cnt1);

    // BN1 coefficients (atomic loads bypass L1 — coherent across XCDs/replays)
    if (tid < 256) {
        float s = 0.f, q = 0.f;
#pragma unroll
        for (int r = 0; r < 8; ++r) {
            s += __hip_atomic_load(&part1[r * 512 + tid], __ATOMIC_RELAXED, __HIP_MEMORY_SCOPE_AGENT);
            q += __hip_atomic_load(&part1[r * 512 + 256 + tid], __ATOMIC_RELAXED, __HIP_MEMORY_SCOPE_AGENT);
        }
        float mu = s * INV_B;
        float var = fmaf(q, INV_B, -mu * mu);
        float rs = rsqrtf(var + BN_EPS_C);
        float a = g1[tid] * rs;
        a1s[tid] = a;
        c1s[tid] = fmaf(-mu, a, be1[tid]);
    }
    __syncthreads();

    // BN1 applied in place to Hs
#pragma unroll
    for (int it = 0; it < 4; ++it) {
        int a = (it * 512 + tid) * 16, r = a >> 9, ks = a & 511;
        int k0 = (ks ^ ((r & 7) << 4)) >> 1;
        bf16x8 hv = *(bf16x8*)(Hs + a);
        bf16x8 sv;
#pragma unroll
        for (int j = 0; j < 8; ++j) {
            float f = bf2f((unsigned short)hv[j]);
            f = fmaf(a1s[k0 + j], f, c1s[k0 + j]);
            sv[j] = (short)f2bf(f);
        }
        *(bf16x8*)(Hs + a) = sv;
    }
    __syncthreads();

    // ---- layer 2: M=64 N=128 K=256; lane owns col n2, 4 m-frags ----
    f32x4 acc2[4];
#pragma unroll
    for (int mi = 0; mi < 4; ++mi) acc2[mi] = (f32x4){0.f, 0.f, 0.f, 0.f};
    const int sx2 = (lr & 7) << 4;
#pragma unroll
    for (int k8 = 0; k8 < 8; ++k8) {
        int kb = (k8 * 64 + lk * 16) ^ sx2;
#pragma unroll
        for (int mi = 0; mi < 4; ++mi) {
            bf16x8 a = *(const bf16x8*)(Hs + (mi * 16 + lr) * 512 + kb);
            acc2[mi] = __builtin_amdgcn_mfma_f32_16x16x32_bf16(a, b2f[k8], acc2[mi], 0, 0, 0);
        }
    }

    // layer-2 epilogue: bias+ReLU+bf16-round in registers; column stats
    {
        float bias = b2[n2];
        float s = 0.f, q = 0.f;
#pragma unroll
        for (int mi = 0; mi < 4; ++mi)
#pragma unroll
            for (int reg = 0; reg < 4; ++reg) {
                float v = fmaxf(acc2[mi][reg] + bias, 0.f);
                float vr = bf2f(f2bf(v));
                acc2[mi][reg] = vr;
                s += vr; q += vr * vr;
            }
        s += __shfl_xor(s, 16); s += __shfl_xor(s, 32);
        q += __shfl_xor(q, 16); q += __shfl_xor(q, 32);
        if (lk == 0) { sstat[n2] = s; sstat[128 + n2] = q; }   // unique writer
    }
    __syncthreads();
    if (tid < 256) atomicAdd(&part2[(size_t)(bid & 7) * 256 + tid], sstat[tid]);

    gbar(cnt2);

    // BN2 folded into W3
    if (tid < 128) {
        float s = 0.f, q = 0.f;
#pragma unroll
        for (int r = 0; r < 8; ++r) {
            s += __hip_atomic_load(&part2[r * 256 + tid], __ATOMIC_RELAXED, __HIP_MEMORY_SCOPE_AGENT);
            q += __hip_atomic_load(&part2[r * 256 + 128 + tid], __ATOMIC_RELAXED, __HIP_MEMORY_SCOPE_AGENT);
        }
        float mu = s * INV_B;
        float var = fmaf(q, INV_B, -mu * mu);
        float rs = rsqrtf(var + BN_EPS_C);
        float a = g2[tid] * rs;
        float c = fmaf(-mu, a, be2[tid]);
        float w3 = W3[tid];
        af[tid] = a * w3;
        cf[tid] = c * w3;
    }
    __syncthreads();
    if (tid < 64) {
        float x = cf[tid] + cf[tid + 64];
        x += __shfl_xor(x, 1);  x += __shfl_xor(x, 2);  x += __shfl_xor(x, 4);
        x += __shfl_xor(x, 8);  x += __shfl_xor(x, 16); x += __shfl_xor(x, 32);
        if (tid == 0) C2s = x;
    }

    // final dot: lane contributes af[n2]*h2[row,n2]; reduce over cols
    float pr[4][4];
#pragma unroll
    for (int mi = 0; mi < 4; ++mi)
#pragma unroll
        for (int reg = 0; reg < 4; ++reg) {
            float t = af[n2] * acc2[mi][reg];
            t += __shfl_xor(t, 1); t += __shfl_xor(t, 2);
            t += __shfl_xor(t, 4); t += __shfl_xor(t, 8);
            pr[mi][reg] = t;
        }
    if (lr == 0) {
#pragma unroll
        for (int mi = 0; mi < 4; ++mi)
#pragma unroll
            for (int reg = 0; reg < 4; ++reg)
                red[w * 64 + mi * 16 + lk * 4 + reg] = pr[mi][reg];
    }
    __syncthreads();
    if (tid < 64) {
        float d = 0.f;
#pragma unroll
        for (int ww = 0; ww < 8; ++ww) d += red[ww * 64 + tid];
        float logit = d + C2s + b3[0] + wide_b[0] + wide_s[tid];
        out[row0 + tid] = 1.f / (1.f + expf(-logit));
    }
}

extern "C" void kernel_launch(void* const* d_in, const int* in_sizes, int n_in,
                              void* d_out, int out_size, void* d_ws, size_t ws_size,
                              hipStream_t stream)
{
    const int*   ui     = (const int*)d_in[0];
    const int*   ii     = (const int*)d_in[1];
    const float* wide_w = (const float*)d_in[2];
    const float* wide_b = (const float*)d_in[3];
    const float* utab   = (const float*)d_in[4];
    const float* itab   = (const float*)d_in[5];
    const float* W1     = (const float*)d_in[6];
    const float* b1     = (const float*)d_in[7];
    const float* g1     = (const float*)d_in[8];
    const float* be1    = (const float*)d_in[9];
    const float* W2     = (const float*)d_in[10];
    const float* b2     = (const float*)d_in[11];
    const float* g2     = (const float*)d_in[12];
    const float* be2    = (const float*)d_in[13];
    const float* W3     = (const float*)d_in[14];
    const float* b3     = (const float*)d_in[15];
    float* outp = (float*)d_out;

    char* base = (char*)d_ws;
    float* part1 = (float*)base;                       // 8 * 512 f32 = 16 KB
    float* part2 = (float*)(base + 16384);             // 8 * 256 f32 = 8 KB
    int*   cnt1  = (int*)(base + 16384 + 8192);
    int*   cnt2  = cnt1 + 1;

    hipMemsetAsync(base, 0, 16384 + 8192 + 8, stream);

    wd_fused<<<NBLK, 512, 0, stream>>>(
        ui, ii, wide_w, wide_b, utab, itab,
        W1, b1, g1, be1, W2, b2, g2, be2, W3, b3,
        part1, part2, cnt1, cnt2, outp);
}

// Round 8
// 39.614 us; speedup vs baseline: 1.6657x; 1.6657x over previous
//
#include <hip/hip_runtime.h>
#include <math.h>

constexpr float INV_B = 1.0f / 16384.0f;
constexpr float BN_EPS_C = 1e-5f;
constexpr int NUM_USERS_C = 1000000;

typedef __attribute__((ext_vector_type(8))) short bf16x8;
typedef __attribute__((ext_vector_type(4))) float f32x4;

__device__ inline unsigned short f2bf(float f) {
    union { float f; unsigned u; } v; v.f = f;
    unsigned r = v.u + 0x7FFFu + ((v.u >> 16) & 1u);   // RNE
    return (unsigned short)(r >> 16);
}
__device__ inline float bf2f(unsigned short h) {
    union { unsigned u; float f; } v; v.u = ((unsigned)h) << 16; return v.f;
}
__device__ inline unsigned cvt_pk(float lo, float hi) {   // RNE, 2 f32 -> 2 bf16
    unsigned d;
    asm("v_cvt_pk_bf16_f32 %0, %1, %2" : "=v"(d) : "v"(lo), "v"(hi));
    return d;
}
__device__ inline bf16x8 pack8(float4 a, float4 b) {
    union { unsigned u[4]; bf16x8 v; } r;
    r.u[0] = cvt_pk(a.x, a.y);
    r.u[1] = cvt_pk(a.z, a.w);
    r.u[2] = cvt_pk(b.x, b.y);
    r.u[3] = cvt_pk(b.z, b.w);
    return r.v;
}
// XOR swizzles for pitch-256B / pitch-512B row-major bf16 tiles
__device__ inline unsigned swz256(int r, int kb) { return (unsigned)(r * 256 + (kb ^ ((r & 7) << 4))); }
__device__ inline unsigned swz512(int r, int kb) { return (unsigned)(r * 512 + (kb ^ ((r & 7) << 4))); }

// ---------------------------------------------------------------------------
// K1: 512 blocks x 32 rows. B-fragments inline-converted per-lane from f32 W1
//     (L2-resident; no LDS staging, no duplication across 8 waves). Gather X
//     -> LDS, GEMM, +b1, ReLU -> h1s image; stats -> part1[16 replicas].
// ---------------------------------------------------------------------------
__global__ __launch_bounds__(512, 4) void wd_k1(
    const int* __restrict__ ui, const int* __restrict__ ii,
    const float* __restrict__ utab, const float* __restrict__ itab,
    const float* __restrict__ W1, const float* __restrict__ b1,
    unsigned short* __restrict__ h1s, float* __restrict__ part1)
{
    __shared__ char Xs[8192];        // 32 x 256B, swizzled
    __shared__ char Bnc[16384];      // bounce: 32 x 512B, swizzled
    __shared__ float sstat[512];

    const int tid = threadIdx.x, bid = blockIdx.x, row0 = bid * 32;
    const int w = tid >> 6, lane = tid & 63, lr = lane & 15, lk = lane >> 4;

    // preload + convert B fragments for this wave's 32 columns (issued first)
    bf16x8 bfr[2][4];
#pragma unroll
    for (int nj = 0; nj < 2; ++nj) {
        int n = w * 32 + nj * 16 + lr;
        const float* wp = W1 + (size_t)n * 128 + lk * 8;
#pragma unroll
        for (int kst = 0; kst < 4; ++kst) {
            float4 va = ((const float4*)(wp + kst * 32))[0];
            float4 vb = ((const float4*)(wp + kst * 32))[1];
            bfr[nj][kst] = pack8(va, vb);
        }
    }

    // stage X: gather + convert (1 chunk per thread)
    {
        int row = tid >> 4, kc = tid & 15;
        const float* src = (kc < 8)
            ? utab + (size_t)ui[row0 + row] * 64 + kc * 8
            : itab + (size_t)ii[row0 + row] * 64 + (kc - 8) * 8;
        float4 a = ((const float4*)src)[0];
        float4 b = ((const float4*)src)[1];
        *(bf16x8*)(Xs + swz256(row, kc * 16)) = pack8(a, b);
    }
    __syncthreads();

    f32x4 acc[2][2];
#pragma unroll
    for (int mi = 0; mi < 2; ++mi)
#pragma unroll
        for (int nj = 0; nj < 2; ++nj) acc[mi][nj] = (f32x4){0.f, 0.f, 0.f, 0.f};

#pragma unroll
    for (int kst = 0; kst < 4; ++kst) {
        int kb = kst * 64 + lk * 16;
        bf16x8 a0 = *(const bf16x8*)(Xs + swz256(lr, kb));
        bf16x8 a1v = *(const bf16x8*)(Xs + swz256(16 + lr, kb));
#pragma unroll
        for (int nj = 0; nj < 2; ++nj) {
            acc[0][nj] = __builtin_amdgcn_mfma_f32_16x16x32_bf16(a0, bfr[nj][kst], acc[0][nj], 0, 0, 0);
            acc[1][nj] = __builtin_amdgcn_mfma_f32_16x16x32_bf16(a1v, bfr[nj][kst], acc[1][nj], 0, 0, 0);
        }
    }

    // epilogue: bias + relu + bf16, bounce to Bnc, per-col stats
#pragma unroll
    for (int nj = 0; nj < 2; ++nj) {
        int col = w * 32 + nj * 16 + lr;
        float bias = b1[col];
        float s = 0.f, q = 0.f;
#pragma unroll
        for (int mi = 0; mi < 2; ++mi)
#pragma unroll
            for (int reg = 0; reg < 4; ++reg) {
                int rl = mi * 16 + lk * 4 + reg;
                float v = fmaxf(acc[mi][nj][reg] + bias, 0.f);
                unsigned short hb = f2bf(v);
                float vr = bf2f(hb);
                s += vr; q += vr * vr;
                *(unsigned short*)(Bnc + swz512(rl, col * 2)) = hb;
            }
        s += __shfl_xor(s, 16); s += __shfl_xor(s, 32);
        q += __shfl_xor(q, 16); q += __shfl_xor(q, 32);
        if (lk == 0) { sstat[col] = s; sstat[256 + col] = q; }   // unique writer per col
    }
    __syncthreads();

    // dump 16 KB tile (32B per thread, coalesced) + stats replica add
    {
        const char* s0 = Bnc + tid * 32;
        char* d0 = (char*)h1s + (size_t)bid * 16384 + tid * 32;
        *(bf16x8*)d0 = *(const bf16x8*)s0;
        *(bf16x8*)(d0 + 16) = *(const bf16x8*)(s0 + 16);
    }
    atomicAdd(&part1[(size_t)(bid & 15) * 512 + tid], sstat[tid]);
}

// ---------------------------------------------------------------------------
// K2: 512 blocks x 32 rows. B-fragments inline-converted per-lane from f32
//     W2; BN1 applied during A staging (value transform, layout preserved).
//     GEMM -> +b2, ReLU -> h2s image; stats -> part2.
// ---------------------------------------------------------------------------
__global__ __launch_bounds__(512, 4) void wd_k2(
    const unsigned short* __restrict__ h1s, const float* __restrict__ part1,
    const float* __restrict__ g1, const float* __restrict__ be1,
    const float* __restrict__ W2, const float* __restrict__ b2,
    unsigned short* __restrict__ h2s, float* __restrict__ part2)
{
    __shared__ char As[16384];       // 32 x 512B, swizzled (h1 image layout)
    __shared__ char Bnc[8192];       // bounce: 32 x 256B, swizzled
    __shared__ float a1s[256], c1s[256], sstat[256];

    const int tid = threadIdx.x, bid = blockIdx.x;
    const int w = tid >> 6, lane = tid & 63, lr = lane & 15, lk = lane >> 4;
    const int n = w * 16 + lr;            // this lane's output column (0..127)

    // preload + convert B fragments: 8 k-slices (issued first)
    bf16x8 bfr[8];
#pragma unroll
    for (int k8 = 0; k8 < 8; ++k8) {
        const float* wp = W2 + (size_t)n * 256 + k8 * 32 + lk * 8;
        float4 va = ((const float4*)wp)[0];
        float4 vb = ((const float4*)wp)[1];
        bfr[k8] = pack8(va, vb);
    }

    // BN1 coefficients from 16 replicas
    if (tid < 256) {
        float s = 0.f, q = 0.f;
#pragma unroll
        for (int r = 0; r < 16; ++r) { s += part1[r * 512 + tid]; q += part1[r * 512 + 256 + tid]; }
        float mu = s * INV_B;
        float var = fmaf(q, INV_B, -mu * mu);
        float rs = rsqrtf(var + BN_EPS_C);
        float a = g1[tid] * rs;
        a1s[tid] = a;
        c1s[tid] = fmaf(-mu, a, be1[tid]);
    }
    __syncthreads();

    // stage A with BN affine (linear copy + value transform)
#pragma unroll
    for (int it = 0; it < 2; ++it) {
        int a = (it * 512 + tid) * 16;
        int r = a >> 9, ks = a & 511;
        int k0 = (ks ^ ((r & 7) << 4)) >> 1;
        bf16x8 hv = *(const bf16x8*)((const char*)h1s + (size_t)bid * 16384 + a);
        bf16x8 sv;
#pragma unroll
        for (int j = 0; j < 8; j += 2) {
            float f0 = fmaf(a1s[k0 + j],     bf2f((unsigned short)hv[j]),     c1s[k0 + j]);
            float f1 = fmaf(a1s[k0 + j + 1], bf2f((unsigned short)hv[j + 1]), c1s[k0 + j + 1]);
            unsigned pk = cvt_pk(f0, f1);
            sv[j]     = (short)(pk & 0xFFFF);
            sv[j + 1] = (short)(pk >> 16);
        }
        *(bf16x8*)(As + a) = sv;
    }
    __syncthreads();

    f32x4 acc[2];
    acc[0] = (f32x4){0.f, 0.f, 0.f, 0.f};
    acc[1] = (f32x4){0.f, 0.f, 0.f, 0.f};
#pragma unroll
    for (int k8 = 0; k8 < 8; ++k8) {
        int kb = (k8 * 64 + lk * 16) ^ ((lr & 7) << 4);   // (16+lr)&7 == lr&7
        bf16x8 a0 = *(const bf16x8*)(As + lr * 512 + kb);
        bf16x8 a1v = *(const bf16x8*)(As + (16 + lr) * 512 + kb);
        acc[0] = __builtin_amdgcn_mfma_f32_16x16x32_bf16(a0, bfr[k8], acc[0], 0, 0, 0);
        acc[1] = __builtin_amdgcn_mfma_f32_16x16x32_bf16(a1v, bfr[k8], acc[1], 0, 0, 0);
    }

    // epilogue
    {
        float bias = b2[n];
        float s = 0.f, q = 0.f;
#pragma unroll
        for (int mi = 0; mi < 2; ++mi)
#pragma unroll
            for (int reg = 0; reg < 4; ++reg) {
                int rl = mi * 16 + lk * 4 + reg;
                float v = fmaxf(acc[mi][reg] + bias, 0.f);
                unsigned short hb = f2bf(v);
                float vr = bf2f(hb);
                s += vr; q += vr * vr;
                *(unsigned short*)(Bnc + swz256(rl, n * 2)) = hb;
            }
        s += __shfl_xor(s, 16); s += __shfl_xor(s, 32);
        q += __shfl_xor(q, 16); q += __shfl_xor(q, 32);
        if (lk == 0) { sstat[n] = s; sstat[128 + n] = q; }
    }
    __syncthreads();

    // dump 8 KB tile + stats replica add
    *(bf16x8*)((char*)h2s + (size_t)bid * 8192 + tid * 16) = *(const bf16x8*)(Bnc + tid * 16);
    if (tid < 256) atomicAdd(&part2[(size_t)(bid & 15) * 256 + tid], sstat[tid]);
}

// ---------------------------------------------------------------------------
// K3: BN2 folded into W3; per-row dot on h2s image (swizzle-aware reads)
//     + wide gather + sigmoid. 256 blocks x 64 rows.
// ---------------------------------------------------------------------------
__global__ __launch_bounds__(256, 2) void wd_k3(
    const int* __restrict__ ui, const int* __restrict__ ii,
    const float* __restrict__ wide_w, const float* __restrict__ wide_b,
    const unsigned short* __restrict__ h2s, const float* __restrict__ part2,
    const float* __restrict__ g2, const float* __restrict__ be2,
    const float* __restrict__ W3, const float* __restrict__ b3,
    float* __restrict__ out)
{
    __shared__ float af[128], cf[128];
    const int tid = threadIdx.x, bid = blockIdx.x;
    const int r = tid >> 2, kq = tid & 3;
    const int row = bid * 64 + r;

    float wide = 0.f;
    if (kq == 0) wide = wide_w[ui[row]] + wide_w[NUM_USERS_C + ii[row]];

    if (tid < 128) {
        float s = 0.f, q = 0.f;
#pragma unroll
        for (int rr = 0; rr < 16; ++rr) { s += part2[rr * 256 + tid]; q += part2[rr * 256 + 128 + tid]; }
        float mu = s * INV_B;
        float var = fmaf(q, INV_B, -mu * mu);
        float rs = rsqrtf(var + BN_EPS_C);
        float a = g2[tid] * rs;
        float c = fmaf(-mu, a, be2[tid]);
        float w3 = W3[tid];
        af[tid] = a * w3;
        cf[tid] = c * w3;
    }
    __syncthreads();

    const int tile = row >> 5, rin = row & 31;
    const char* tb = (const char*)h2s + (size_t)tile * 8192 + rin * 256;
    float acc = 0.f;
#pragma unroll
    for (int j = 0; j < 4; ++j) {
        int ks = (kq * 64 + j * 16) ^ ((rin & 7) << 4);
        bf16x8 hv = *(const bf16x8*)(tb + ks);
#pragma unroll
        for (int e = 0; e < 8; ++e) {
            float h = bf2f((unsigned short)hv[e]);
            int k = kq * 32 + j * 8 + e;
            acc += fmaf(h, af[k], cf[k]);
        }
    }
    acc += __shfl_xor(acc, 1);
    acc += __shfl_xor(acc, 2);
    if (kq == 0) {
        float logit = acc + b3[0] + wide_b[0] + wide;
        out[row] = 1.f / (1.f + expf(-logit));
    }
}

extern "C" void kernel_launch(void* const* d_in, const int* in_sizes, int n_in,
                              void* d_out, int out_size, void* d_ws, size_t ws_size,
                              hipStream_t stream)
{
    const int*   ui     = (const int*)d_in[0];
    const int*   ii     = (const int*)d_in[1];
    const float* wide_w = (const float*)d_in[2];
    const float* wide_b = (const float*)d_in[3];
    const float* utab   = (const float*)d_in[4];
    const float* itab   = (const float*)d_in[5];
    const float* W1     = (const float*)d_in[6];
    const float* b1     = (const float*)d_in[7];
    const float* g1     = (const float*)d_in[8];
    const float* be1    = (const float*)d_in[9];
    const float* W2     = (const float*)d_in[10];
    const float* b2     = (const float*)d_in[11];
    const float* g2     = (const float*)d_in[12];
    const float* be2    = (const float*)d_in[13];
    const float* W3     = (const float*)d_in[14];
    const float* b3     = (const float*)d_in[15];
    float* outp = (float*)d_out;

    char* base = (char*)d_ws;
    float* part1 = (float*)base;                                   // 16*512 f32 = 32 KB
    float* part2 = (float*)(base + 32768);                         // 16*256 f32 = 16 KB
    unsigned short* h1s = (unsigned short*)(base + 49152);         // 512 tiles * 16 KB
    unsigned short* h2s = (unsigned short*)(base + 49152 + (size_t)512 * 16384);

    hipMemsetAsync(base, 0, 49152, stream);

    wd_k1<<<512, 512, 0, stream>>>(ui, ii, utab, itab, W1, b1, h1s, part1);
    wd_k2<<<512, 512, 0, stream>>>(h1s, part1, g1, be1, W2, b2, h2s, part2);
    wd_k3<<<256, 256, 0, stream>>>(ui, ii, wide_w, wide_b, h2s, part2, g2, be2, W3, b3, outp);
}

// Round 9
// 39.105 us; speedup vs baseline: 1.6874x; 1.0130x over previous
//
#include <hip/hip_runtime.h>
#include <math.h>

constexpr float INV_B = 1.0f / 16384.0f;
constexpr float BN_EPS_C = 1e-5f;
constexpr int NUM_USERS_C = 1000000;

typedef __attribute__((ext_vector_type(8))) short bf16x8;
typedef __attribute__((ext_vector_type(4))) float f32x4;

__device__ inline unsigned short f2bf(float f) {
    union { float f; unsigned u; } v; v.f = f;
    unsigned r = v.u + 0x7FFFu + ((v.u >> 16) & 1u);   // RNE
    return (unsigned short)(r >> 16);
}
__device__ inline float bf2f(unsigned short h) {
    union { unsigned u; float f; } v; v.u = ((unsigned)h) << 16; return v.f;
}
__device__ inline bf16x8 pack8(float4 a, float4 b) {
    bf16x8 sv;
    sv[0] = (short)f2bf(a.x); sv[1] = (short)f2bf(a.y);
    sv[2] = (short)f2bf(a.z); sv[3] = (short)f2bf(a.w);
    sv[4] = (short)f2bf(b.x); sv[5] = (short)f2bf(b.y);
    sv[6] = (short)f2bf(b.z); sv[7] = (short)f2bf(b.w);
    return sv;
}
// XOR swizzles for pitch-256B / pitch-512B row-major bf16 tiles
__device__ inline unsigned swz256(int r, int kb) { return (unsigned)(r * 256 + (kb ^ ((r & 7) << 4))); }
__device__ inline unsigned swz512(int r, int kb) { return (unsigned)(r * 512 + (kb ^ ((r & 7) << 4))); }

// ---------------------------------------------------------------------------
// K1: 512 blocks x 32 rows. B-fragments inline-converted per-lane from f32 W1
//     (L2-resident; no LDS staging, no duplication across 8 waves). Gather X
//     -> LDS, GEMM, +b1, ReLU -> h1s image; stats -> part1[16 replicas].
// ---------------------------------------------------------------------------
__global__ __launch_bounds__(512, 4) void wd_k1(
    const int* __restrict__ ui, const int* __restrict__ ii,
    const float* __restrict__ utab, const float* __restrict__ itab,
    const float* __restrict__ W1, const float* __restrict__ b1,
    unsigned short* __restrict__ h1s, float* __restrict__ part1)
{
    __shared__ char Xs[8192];        // 32 x 256B, swizzled
    __shared__ char Bnc[16384];      // bounce: 32 x 512B, swizzled
    __shared__ float sstat[512];

    const int tid = threadIdx.x, bid = blockIdx.x, row0 = bid * 32;
    const int w = tid >> 6, lane = tid & 63, lr = lane & 15, lk = lane >> 4;

    // stage X: gather + convert (1 chunk per thread) — longest latency, issue first
    {
        int row = tid >> 4, kc = tid & 15;
        const float* src = (kc < 8)
            ? utab + (size_t)ui[row0 + row] * 64 + kc * 8
            : itab + (size_t)ii[row0 + row] * 64 + (kc - 8) * 8;
        float4 a = ((const float4*)src)[0];
        float4 b = ((const float4*)src)[1];
        *(bf16x8*)(Xs + swz256(row, kc * 16)) = pack8(a, b);
    }

    // preload + convert B fragments for this wave's 32 columns (bit-twiddle)
    bf16x8 bfr[2][4];
#pragma unroll
    for (int nj = 0; nj < 2; ++nj) {
        int n = w * 32 + nj * 16 + lr;
        const float* wp = W1 + (size_t)n * 128 + lk * 8;
#pragma unroll
        for (int kst = 0; kst < 4; ++kst) {
            float4 va = ((const float4*)(wp + kst * 32))[0];
            float4 vb = ((const float4*)(wp + kst * 32))[1];
            bfr[nj][kst] = pack8(va, vb);
        }
    }
    __syncthreads();

    f32x4 acc[2][2];
#pragma unroll
    for (int mi = 0; mi < 2; ++mi)
#pragma unroll
        for (int nj = 0; nj < 2; ++nj) acc[mi][nj] = (f32x4){0.f, 0.f, 0.f, 0.f};

#pragma unroll
    for (int kst = 0; kst < 4; ++kst) {
        int kb = kst * 64 + lk * 16;
        bf16x8 a0 = *(const bf16x8*)(Xs + swz256(lr, kb));
        bf16x8 a1v = *(const bf16x8*)(Xs + swz256(16 + lr, kb));
#pragma unroll
        for (int nj = 0; nj < 2; ++nj) {
            acc[0][nj] = __builtin_amdgcn_mfma_f32_16x16x32_bf16(a0, bfr[nj][kst], acc[0][nj], 0, 0, 0);
            acc[1][nj] = __builtin_amdgcn_mfma_f32_16x16x32_bf16(a1v, bfr[nj][kst], acc[1][nj], 0, 0, 0);
        }
    }

    // epilogue: bias + relu + bf16, bounce to Bnc, per-col stats
#pragma unroll
    for (int nj = 0; nj < 2; ++nj) {
        int col = w * 32 + nj * 16 + lr;
        float bias = b1[col];
        float s = 0.f, q = 0.f;
#pragma unroll
        for (int mi = 0; mi < 2; ++mi)
#pragma unroll
            for (int reg = 0; reg < 4; ++reg) {
                int rl = mi * 16 + lk * 4 + reg;
                float v = fmaxf(acc[mi][nj][reg] + bias, 0.f);
                unsigned short hb = f2bf(v);
                float vr = bf2f(hb);
                s += vr; q += vr * vr;
                *(unsigned short*)(Bnc + swz512(rl, col * 2)) = hb;
            }
        s += __shfl_xor(s, 16); s += __shfl_xor(s, 32);
        q += __shfl_xor(q, 16); q += __shfl_xor(q, 32);
        if (lk == 0) { sstat[col] = s; sstat[256 + col] = q; }   // unique writer per col
    }
    __syncthreads();

    // dump 16 KB tile (32B per thread, coalesced) + stats replica add
    {
        const char* s0 = Bnc + tid * 32;
        char* d0 = (char*)h1s + (size_t)bid * 16384 + tid * 32;
        *(bf16x8*)d0 = *(const bf16x8*)s0;
        *(bf16x8*)(d0 + 16) = *(const bf16x8*)(s0 + 16);
    }
    atomicAdd(&part1[(size_t)(bid & 15) * 512 + tid], sstat[tid]);
}

// ---------------------------------------------------------------------------
// K2: 512 blocks x 32 rows. B-fragments inline-converted per-lane from f32
//     W2; BN1 applied during A staging (value transform, layout preserved).
//     GEMM -> +b2, ReLU -> h2s image; stats -> part2.
// ---------------------------------------------------------------------------
__global__ __launch_bounds__(512, 4) void wd_k2(
    const unsigned short* __restrict__ h1s, const float* __restrict__ part1,
    const float* __restrict__ g1, const float* __restrict__ be1,
    const float* __restrict__ W2, const float* __restrict__ b2,
    unsigned short* __restrict__ h2s, float* __restrict__ part2)
{
    __shared__ char As[16384];       // 32 x 512B, swizzled (h1 image layout)
    __shared__ char Bnc[8192];       // bounce: 32 x 256B, swizzled
    __shared__ float a1s[256], c1s[256], sstat[256];

    const int tid = threadIdx.x, bid = blockIdx.x;
    const int w = tid >> 6, lane = tid & 63, lr = lane & 15, lk = lane >> 4;
    const int n = w * 16 + lr;            // this lane's output column (0..127)

    // preload + convert B fragments: 8 k-slices (bit-twiddle)
    bf16x8 bfr[8];
#pragma unroll
    for (int k8 = 0; k8 < 8; ++k8) {
        const float* wp = W2 + (size_t)n * 256 + k8 * 32 + lk * 8;
        float4 va = ((const float4*)wp)[0];
        float4 vb = ((const float4*)wp)[1];
        bfr[k8] = pack8(va, vb);
    }

    // BN1 coefficients from 16 replicas
    if (tid < 256) {
        float s = 0.f, q = 0.f;
#pragma unroll
        for (int r = 0; r < 16; ++r) { s += part1[r * 512 + tid]; q += part1[r * 512 + 256 + tid]; }
        float mu = s * INV_B;
        float var = fmaf(q, INV_B, -mu * mu);
        float rs = rsqrtf(var + BN_EPS_C);
        float a = g1[tid] * rs;
        a1s[tid] = a;
        c1s[tid] = fmaf(-mu, a, be1[tid]);
    }
    __syncthreads();

    // stage A with BN affine (linear copy + value transform, scalar path)
#pragma unroll
    for (int it = 0; it < 2; ++it) {
        int a = (it * 512 + tid) * 16;
        int r = a >> 9, ks = a & 511;
        int k0 = (ks ^ ((r & 7) << 4)) >> 1;
        bf16x8 hv = *(const bf16x8*)((const char*)h1s + (size_t)bid * 16384 + a);
        bf16x8 sv;
#pragma unroll
        for (int j = 0; j < 8; ++j) {
            float f = bf2f((unsigned short)hv[j]);
            f = fmaf(a1s[k0 + j], f, c1s[k0 + j]);
            sv[j] = (short)f2bf(f);
        }
        *(bf16x8*)(As + a) = sv;
    }
    __syncthreads();

    f32x4 acc[2];
    acc[0] = (f32x4){0.f, 0.f, 0.f, 0.f};
    acc[1] = (f32x4){0.f, 0.f, 0.f, 0.f};
#pragma unroll
    for (int k8 = 0; k8 < 8; ++k8) {
        int kb = (k8 * 64 + lk * 16) ^ ((lr & 7) << 4);   // (16+lr)&7 == lr&7
        bf16x8 a0 = *(const bf16x8*)(As + lr * 512 + kb);
        bf16x8 a1v = *(const bf16x8*)(As + (16 + lr) * 512 + kb);
        acc[0] = __builtin_amdgcn_mfma_f32_16x16x32_bf16(a0, bfr[k8], acc[0], 0, 0, 0);
        acc[1] = __builtin_amdgcn_mfma_f32_16x16x32_bf16(a1v, bfr[k8], acc[1], 0, 0, 0);
    }

    // epilogue
    {
        float bias = b2[n];
        float s = 0.f, q = 0.f;
#pragma unroll
        for (int mi = 0; mi < 2; ++mi)
#pragma unroll
            for (int reg = 0; reg < 4; ++reg) {
                int rl = mi * 16 + lk * 4 + reg;
                float v = fmaxf(acc[mi][reg] + bias, 0.f);
                unsigned short hb = f2bf(v);
                float vr = bf2f(hb);
                s += vr; q += vr * vr;
                *(unsigned short*)(Bnc + swz256(rl, n * 2)) = hb;
            }
        s += __shfl_xor(s, 16); s += __shfl_xor(s, 32);
        q += __shfl_xor(q, 16); q += __shfl_xor(q, 32);
        if (lk == 0) { sstat[n] = s; sstat[128 + n] = q; }
    }
    __syncthreads();

    // dump 8 KB tile + stats replica add
    *(bf16x8*)((char*)h2s + (size_t)bid * 8192 + tid * 16) = *(const bf16x8*)(Bnc + tid * 16);
    if (tid < 256) atomicAdd(&part2[(size_t)(bid & 15) * 256 + tid], sstat[tid]);
}

// ---------------------------------------------------------------------------
// K3: BN2 folded into W3; per-row dot on h2s image (swizzle-aware reads)
//     + wide gather + sigmoid. 256 blocks x 64 rows.
// ---------------------------------------------------------------------------
__global__ __launch_bounds__(256, 2) void wd_k3(
    const int* __restrict__ ui, const int* __restrict__ ii,
    const float* __restrict__ wide_w, const float* __restrict__ wide_b,
    const unsigned short* __restrict__ h2s, const float* __restrict__ part2,
    const float* __restrict__ g2, const float* __restrict__ be2,
    const float* __restrict__ W3, const float* __restrict__ b3,
    float* __restrict__ out)
{
    __shared__ float af[128], cf[128];
    const int tid = threadIdx.x, bid = blockIdx.x;
    const int r = tid >> 2, kq = tid & 3;
    const int row = bid * 64 + r;

    float wide = 0.f;
    if (kq == 0) wide = wide_w[ui[row]] + wide_w[NUM_USERS_C + ii[row]];

    if (tid < 128) {
        float s = 0.f, q = 0.f;
#pragma unroll
        for (int rr = 0; rr < 16; ++rr) { s += part2[rr * 256 + tid]; q += part2[rr * 256 + 128 + tid]; }
        float mu = s * INV_B;
        float var = fmaf(q, INV_B, -mu * mu);
        float rs = rsqrtf(var + BN_EPS_C);
        float a = g2[tid] * rs;
        float c = fmaf(-mu, a, be2[tid]);
        float w3 = W3[tid];
        af[tid] = a * w3;
        cf[tid] = c * w3;
    }
    __syncthreads();

    const int tile = row >> 5, rin = row & 31;
    const char* tb = (const char*)h2s + (size_t)tile * 8192 + rin * 256;
    float acc = 0.f;
#pragma unroll
    for (int j = 0; j < 4; ++j) {
        int ks = (kq * 64 + j * 16) ^ ((rin & 7) << 4);
        bf16x8 hv = *(const bf16x8*)(tb + ks);
#pragma unroll
        for (int e = 0; e < 8; ++e) {
            float h = bf2f((unsigned short)hv[e]);
            int k = kq * 32 + j * 8 + e;
            acc += fmaf(h, af[k], cf[k]);
        }
    }
    acc += __shfl_xor(acc, 1);
    acc += __shfl_xor(acc, 2);
    if (kq == 0) {
        float logit = acc + b3[0] + wide_b[0] + wide;
        out[row] = 1.f / (1.f + expf(-logit));
    }
}

extern "C" void kernel_launch(void* const* d_in, const int* in_sizes, int n_in,
                              void* d_out, int out_size, void* d_ws, size_t ws_size,
                              hipStream_t stream)
{
    const int*   ui     = (const int*)d_in[0];
    const int*   ii     = (const int*)d_in[1];
    const float* wide_w = (const float*)d_in[2];
    const float* wide_b = (const float*)d_in[3];
    const float* utab   = (const float*)d_in[4];
    const float* itab   = (const float*)d_in[5];
    const float* W1     = (const float*)d_in[6];
    const float* b1     = (const float*)d_in[7];
    const float* g1     = (const float*)d_in[8];
    const float* be1    = (const float*)d_in[9];
    const float* W2     = (const float*)d_in[10];
    const float* b2     = (const float*)d_in[11];
    const float* g2     = (const float*)d_in[12];
    const float* be2    = (const float*)d_in[13];
    const float* W3     = (const float*)d_in[14];
    const float* b3     = (const float*)d_in[15];
    float* outp = (float*)d_out;

    char* base = (char*)d_ws;
    float* part1 = (float*)base;                                   // 16*512 f32 = 32 KB
    float* part2 = (float*)(base + 32768);                         // 16*256 f32 = 16 KB
    unsigned short* h1s = (unsigned short*)(base + 49152);         // 512 tiles * 16 KB
    unsigned short* h2s = (unsigned short*)(base + 49152 + (size_t)512 * 16384);

    hipMemsetAsync(base, 0, 49152, stream);

    wd_k1<<<512, 512, 0, stream>>>(ui, ii, utab, itab, W1, b1, h1s, part1);
    wd_k2<<<512, 512, 0, stream>>>(h1s, part1, g1, be1, W2, b2, h2s, part2);
    wd_k3<<<256, 256, 0, stream>>>(ui, ii, wide_w, wide_b, h2s, part2, g2, be2, W3, b3, outp);
}

// Round 10
// 25.752 us; speedup vs baseline: 2.5624x; 1.5185x over previous
//
#include <hip/hip_runtime.h>
#include <math.h>

constexpr float INV_B = 1.0f / 16384.0f;
constexpr float BN_EPS_C = 1e-5f;
constexpr int NUM_USERS_C = 1000000;

typedef __attribute__((ext_vector_type(8))) short bf16x8;
typedef __attribute__((ext_vector_type(4))) float f32x4;

__device__ inline unsigned short f2bf(float f) {
    union { float f; unsigned u; } v; v.f = f;
    unsigned r = v.u + 0x7FFFu + ((v.u >> 16) & 1u);   // RNE
    return (unsigned short)(r >> 16);
}
__device__ inline float bf2f(unsigned short h) {
    union { unsigned u; float f; } v; v.u = ((unsigned)h) << 16; return v.f;
}
__device__ inline bf16x8 pack8(float4 a, float4 b) {
    bf16x8 sv;
    sv[0] = (short)f2bf(a.x); sv[1] = (short)f2bf(a.y);
    sv[2] = (short)f2bf(a.z); sv[3] = (short)f2bf(a.w);
    sv[4] = (short)f2bf(b.x); sv[5] = (short)f2bf(b.y);
    sv[6] = (short)f2bf(b.z); sv[7] = (short)f2bf(b.w);
    return sv;
}
// XOR swizzles for pitch-256B / pitch-512B row-major bf16 tiles
__device__ inline unsigned swz256(int r, int kb) { return (unsigned)(r * 256 + (kb ^ ((r & 7) << 4))); }
__device__ inline unsigned swz512(int r, int kb) { return (unsigned)(r * 512 + (kb ^ ((r & 7) << 4))); }

// ---------------------------------------------------------------------------
// K0: one-time weight conversion f32 -> bf16 fragment-image layout, plus
//     zeroing of the stat replica buffers (no separate memset node).
// img1: W1 as [256 n][256B k] swizzled. img2: W2 as 2 k-halves, each
//       [128 n][256B] swizzled (half h covers k in [128h,128h+128)).
// ---------------------------------------------------------------------------
__global__ __launch_bounds__(256) void wd_k0(
    const float* __restrict__ W1, const float* __restrict__ W2,
    unsigned short* __restrict__ img1, unsigned short* __restrict__ img2,
    float* __restrict__ stats)
{
    int t = blockIdx.x * 256 + threadIdx.x;        // grid 48*256 = 12288
    if (t < 12288) stats[t] = 0.f;
    if (t < 4096) {
        int a = t * 16, n = a >> 8, ks = a & 255;
        int k0 = (ks ^ ((n & 7) << 4)) >> 1;
        const float* src = W1 + (size_t)n * 128 + k0;
        float4 va = ((const float4*)src)[0];
        float4 vb = ((const float4*)src)[1];
        *(bf16x8*)((char*)img1 + a) = pack8(va, vb);
    } else if (t < 8192) {
        int tt = t - 4096;
        int a = tt * 16, h = a >> 15, rem = a & 32767, n = rem >> 8, ks = rem & 255;
        int kb = ks ^ ((n & 7) << 4);
        int k0 = h * 128 + (kb >> 1);
        const float* src = W2 + (size_t)n * 256 + k0;
        float4 va = ((const float4*)src)[0];
        float4 vb = ((const float4*)src)[1];
        *(bf16x8*)((char*)img2 + a) = pack8(va, vb);
    }
}

// ---------------------------------------------------------------------------
// K1: 512 blocks x 32 rows. X-gather issued first (HBM random, longest
//     latency); B-fragments preloaded per-lane from bf16 img1 (L2-hot, no
//     LDS staging, no duplication across 8 waves). GEMM, +b1, ReLU -> h1s
//     image; stats -> part1[16 replicas]. 2 barriers.
// ---------------------------------------------------------------------------
__global__ __launch_bounds__(512, 4) void wd_k1(
    const int* __restrict__ ui, const int* __restrict__ ii,
    const float* __restrict__ utab, const float* __restrict__ itab,
    const unsigned short* __restrict__ img1, const float* __restrict__ b1,
    unsigned short* __restrict__ h1s, float* __restrict__ part1)
{
    __shared__ char Xs[8192];        // 32 x 256B, swizzled
    __shared__ char Bnc[16384];      // bounce: 32 x 512B, swizzled
    __shared__ float sstat[512];

    const int tid = threadIdx.x, bid = blockIdx.x, row0 = bid * 32;
    const int w = tid >> 6, lane = tid & 63, lr = lane & 15, lk = lane >> 4;

    // issue X-gather loads first (random HBM ~900cy)
    const int grow = tid >> 4, gkc = tid & 15;
    const float* gsrc = (gkc < 8)
        ? utab + (size_t)ui[row0 + grow] * 64 + gkc * 8
        : itab + (size_t)ii[row0 + grow] * 64 + (gkc - 8) * 8;
    float4 gva = ((const float4*)gsrc)[0];
    float4 gvb = ((const float4*)gsrc)[1];

    // preload B fragments for this wave's 32 columns (bf16 image, L2-hot)
    bf16x8 bfr[2][4];
#pragma unroll
    for (int nj = 0; nj < 2; ++nj) {
        int n = w * 32 + nj * 16 + lr;
        const char* bp = (const char*)img1 + n * 256;
        int sx = (n & 7) << 4;
#pragma unroll
        for (int kst = 0; kst < 4; ++kst)
            bfr[nj][kst] = *(const bf16x8*)(bp + ((kst * 64 + lk * 16) ^ sx));
    }

    // write gathered X to LDS
    *(bf16x8*)(Xs + swz256(grow, gkc * 16)) = pack8(gva, gvb);
    __syncthreads();

    f32x4 acc[2][2];
#pragma unroll
    for (int mi = 0; mi < 2; ++mi)
#pragma unroll
        for (int nj = 0; nj < 2; ++nj) acc[mi][nj] = (f32x4){0.f, 0.f, 0.f, 0.f};

#pragma unroll
    for (int kst = 0; kst < 4; ++kst) {
        int kb = kst * 64 + lk * 16;
        bf16x8 a0 = *(const bf16x8*)(Xs + swz256(lr, kb));
        bf16x8 a1v = *(const bf16x8*)(Xs + swz256(16 + lr, kb));
#pragma unroll
        for (int nj = 0; nj < 2; ++nj) {
            acc[0][nj] = __builtin_amdgcn_mfma_f32_16x16x32_bf16(a0, bfr[nj][kst], acc[0][nj], 0, 0, 0);
            acc[1][nj] = __builtin_amdgcn_mfma_f32_16x16x32_bf16(a1v, bfr[nj][kst], acc[1][nj], 0, 0, 0);
        }
    }

    // epilogue: bias + relu + bf16, bounce to Bnc, per-col stats
#pragma unroll
    for (int nj = 0; nj < 2; ++nj) {
        int col = w * 32 + nj * 16 + lr;
        float bias = b1[col];
        float s = 0.f, q = 0.f;
#pragma unroll
        for (int mi = 0; mi < 2; ++mi)
#pragma unroll
            for (int reg = 0; reg < 4; ++reg) {
                int rl = mi * 16 + lk * 4 + reg;
                float v = fmaxf(acc[mi][nj][reg] + bias, 0.f);
                unsigned short hb = f2bf(v);
                float vr = bf2f(hb);
                s += vr; q += vr * vr;
                *(unsigned short*)(Bnc + swz512(rl, col * 2)) = hb;
            }
        s += __shfl_xor(s, 16); s += __shfl_xor(s, 32);
        q += __shfl_xor(q, 16); q += __shfl_xor(q, 32);
        if (lk == 0) { sstat[col] = s; sstat[256 + col] = q; }   // unique writer per col
    }
    __syncthreads();

    // dump 16 KB tile (32B per thread, coalesced) + stats replica add
    {
        const char* s0 = Bnc + tid * 32;
        char* d0 = (char*)h1s + (size_t)bid * 16384 + tid * 32;
        *(bf16x8*)d0 = *(const bf16x8*)s0;
        *(bf16x8*)(d0 + 16) = *(const bf16x8*)(s0 + 16);
    }
    atomicAdd(&part1[(size_t)(bid & 15) * 512 + tid], sstat[tid]);
}

// ---------------------------------------------------------------------------
// K2: 512 blocks x 32 rows. T14 split: raw h1 tile loads issued to registers
//     FIRST, BN coeffs + B-preload (img2) computed under that latency, then
//     transform + ds_write after the barrier. GEMM -> +b2, ReLU -> h2s image;
//     stats -> part2.
// ---------------------------------------------------------------------------
__global__ __launch_bounds__(512, 4) void wd_k2(
    const unsigned short* __restrict__ h1s, const float* __restrict__ part1,
    const float* __restrict__ g1, const float* __restrict__ be1,
    const unsigned short* __restrict__ img2, const float* __restrict__ b2,
    unsigned short* __restrict__ h2s, float* __restrict__ part2)
{
    __shared__ char As[16384];       // 32 x 512B, swizzled (h1 image layout)
    __shared__ char Bnc[8192];       // bounce: 32 x 256B, swizzled
    __shared__ float a1s[256], c1s[256], sstat[256];

    const int tid = threadIdx.x, bid = blockIdx.x;
    const int w = tid >> 6, lane = tid & 63, lr = lane & 15, lk = lane >> 4;
    const int n = w * 16 + lr;            // this lane's output column (0..127)
    const int sx = (n & 7) << 4;

    // (1) issue raw A-tile loads to registers (L3/HBM latency starts now)
    bf16x8 hv0 = *(const bf16x8*)((const char*)h1s + (size_t)bid * 16384 + tid * 16);
    bf16x8 hv1 = *(const bf16x8*)((const char*)h1s + (size_t)bid * 16384 + 8192 + tid * 16);

    // (2) preload B fragments from img2 (L2-hot)
    bf16x8 bfr[8];
#pragma unroll
    for (int h = 0; h < 2; ++h)
#pragma unroll
        for (int kst = 0; kst < 4; ++kst)
            bfr[h * 4 + kst] = *(const bf16x8*)((const char*)img2 + h * 32768 + n * 256 + ((kst * 64 + lk * 16) ^ sx));

    // (3) BN1 coefficients from 16 replicas
    if (tid < 256) {
        float s = 0.f, q = 0.f;
#pragma unroll
        for (int r = 0; r < 16; ++r) { s += part1[r * 512 + tid]; q += part1[r * 512 + 256 + tid]; }
        float mu = s * INV_B;
        float var = fmaf(q, INV_B, -mu * mu);
        float rs = rsqrtf(var + BN_EPS_C);
        float a = g1[tid] * rs;
        a1s[tid] = a;
        c1s[tid] = fmaf(-mu, a, be1[tid]);
    }
    __syncthreads();

    // (4) transform + write A tile (value transform, layout preserved)
#pragma unroll
    for (int it = 0; it < 2; ++it) {
        int a = it * 8192 + tid * 16;
        int r = a >> 9, ks = a & 511;
        int k0 = (ks ^ ((r & 7) << 4)) >> 1;
        bf16x8 hv = it ? hv1 : hv0;
        bf16x8 sv;
#pragma unroll
        for (int j = 0; j < 8; ++j) {
            float f = bf2f((unsigned short)hv[j]);
            f = fmaf(a1s[k0 + j], f, c1s[k0 + j]);
            sv[j] = (short)f2bf(f);
        }
        *(bf16x8*)(As + a) = sv;
    }
    __syncthreads();

    f32x4 acc[2];
    acc[0] = (f32x4){0.f, 0.f, 0.f, 0.f};
    acc[1] = (f32x4){0.f, 0.f, 0.f, 0.f};
#pragma unroll
    for (int k8 = 0; k8 < 8; ++k8) {
        int kb = (k8 * 64 + lk * 16) ^ ((lr & 7) << 4);   // (16+lr)&7 == lr&7
        bf16x8 a0 = *(const bf16x8*)(As + lr * 512 + kb);
        bf16x8 a1v = *(const bf16x8*)(As + (16 + lr) * 512 + kb);
        acc[0] = __builtin_amdgcn_mfma_f32_16x16x32_bf16(a0, bfr[k8], acc[0], 0, 0, 0);
        acc[1] = __builtin_amdgcn_mfma_f32_16x16x32_bf16(a1v, bfr[k8], acc[1], 0, 0, 0);
    }

    // epilogue
    {
        float bias = b2[n];
        float s = 0.f, q = 0.f;
#pragma unroll
        for (int mi = 0; mi < 2; ++mi)
#pragma unroll
            for (int reg = 0; reg < 4; ++reg) {
                int rl = mi * 16 + lk * 4 + reg;
                float v = fmaxf(acc[mi][reg] + bias, 0.f);
                unsigned short hb = f2bf(v);
                float vr = bf2f(hb);
                s += vr; q += vr * vr;
                *(unsigned short*)(Bnc + swz256(rl, n * 2)) = hb;
            }
        s += __shfl_xor(s, 16); s += __shfl_xor(s, 32);
        q += __shfl_xor(q, 16); q += __shfl_xor(q, 32);
        if (lk == 0) { sstat[n] = s; sstat[128 + n] = q; }
    }
    __syncthreads();

    // dump 8 KB tile + stats replica add
    *(bf16x8*)((char*)h2s + (size_t)bid * 8192 + tid * 16) = *(const bf16x8*)(Bnc + tid * 16);
    if (tid < 256) atomicAdd(&part2[(size_t)(bid & 15) * 256 + tid], sstat[tid]);
}

// ---------------------------------------------------------------------------
// K3: BN2 folded into W3; per-row dot on h2s image (swizzle-aware reads)
//     + wide gather + sigmoid. 512 blocks x 32 rows.
// ---------------------------------------------------------------------------
__global__ __launch_bounds__(128, 4) void wd_k3(
    const int* __restrict__ ui, const int* __restrict__ ii,
    const float* __restrict__ wide_w, const float* __restrict__ wide_b,
    const unsigned short* __restrict__ h2s, const float* __restrict__ part2,
    const float* __restrict__ g2, const float* __restrict__ be2,
    const float* __restrict__ W3, const float* __restrict__ b3,
    float* __restrict__ out)
{
    __shared__ float af[128], cf[128];
    const int tid = threadIdx.x, bid = blockIdx.x;
    const int r = tid >> 2, kq = tid & 3;
    const int row = bid * 32 + r;

    float wide = 0.f;
    if (kq == 0) wide = wide_w[ui[row]] + wide_w[NUM_USERS_C + ii[row]];

    {
        float s = 0.f, q = 0.f;
#pragma unroll
        for (int rr = 0; rr < 16; ++rr) { s += part2[rr * 256 + tid]; q += part2[rr * 256 + 128 + tid]; }
        float mu = s * INV_B;
        float var = fmaf(q, INV_B, -mu * mu);
        float rs = rsqrtf(var + BN_EPS_C);
        float a = g2[tid] * rs;
        float c = fmaf(-mu, a, be2[tid]);
        float w3 = W3[tid];
        af[tid] = a * w3;
        cf[tid] = c * w3;
    }
    __syncthreads();

    const char* tb = (const char*)h2s + (size_t)bid * 8192 + r * 256;
    float acc = 0.f;
#pragma unroll
    for (int j = 0; j < 4; ++j) {
        int ks = (kq * 64 + j * 16) ^ ((r & 7) << 4);
        bf16x8 hv = *(const bf16x8*)(tb + ks);
#pragma unroll
        for (int e = 0; e < 8; ++e) {
            float h = bf2f((unsigned short)hv[e]);
            int k = kq * 32 + j * 8 + e;
            acc += fmaf(h, af[k], cf[k]);
        }
    }
    acc += __shfl_xor(acc, 1);
    acc += __shfl_xor(acc, 2);
    if (kq == 0) {
        float logit = acc + b3[0] + wide_b[0] + wide;
        out[row] = 1.f / (1.f + expf(-logit));
    }
}

extern "C" void kernel_launch(void* const* d_in, const int* in_sizes, int n_in,
                              void* d_out, int out_size, void* d_ws, size_t ws_size,
                              hipStream_t stream)
{
    const int*   ui     = (const int*)d_in[0];
    const int*   ii     = (const int*)d_in[1];
    const float* wide_w = (const float*)d_in[2];
    const float* wide_b = (const float*)d_in[3];
    const float* utab   = (const float*)d_in[4];
    const float* itab   = (const float*)d_in[5];
    const float* W1     = (const float*)d_in[6];
    const float* b1     = (const float*)d_in[7];
    const float* g1     = (const float*)d_in[8];
    const float* be1    = (const float*)d_in[9];
    const float* W2     = (const float*)d_in[10];
    const float* b2     = (const float*)d_in[11];
    const float* g2     = (const float*)d_in[12];
    const float* be2    = (const float*)d_in[13];
    const float* W3     = (const float*)d_in[14];
    const float* b3     = (const float*)d_in[15];
    float* outp = (float*)d_out;

    char* base = (char*)d_ws;
    float* part1 = (float*)base;                                   // 16*512 f32
    float* part2 = (float*)(base + 16 * 512 * 4);                  // 16*256 f32
    unsigned short* img1 = (unsigned short*)(base + 49152);        // 64 KB
    unsigned short* img2 = (unsigned short*)(base + 49152 + 65536);
    unsigned short* h1s  = (unsigned short*)(base + 49152 + 131072);              // 8 MB
    unsigned short* h2s  = (unsigned short*)(base + 49152 + 131072 + (size_t)512 * 16384);

    wd_k0<<<48, 256, 0, stream>>>(W1, W2, img1, img2, part1);
    wd_k1<<<512, 512, 0, stream>>>(ui, ii, utab, itab, img1, b1, h1s, part1);
    wd_k2<<<512, 512, 0, stream>>>(h1s, part1, g1, be1, img2, b2, h2s, part2);
    wd_k3<<<512, 128, 0, stream>>>(ui, ii, wide_w, wide_b, h2s, part2, g2, be2, W3, b3, outp);
}

// Round 11
// 25.637 us; speedup vs baseline: 2.5738x; 1.0045x over previous
//
#include <hip/hip_runtime.h>
#include <math.h>

constexpr float INV_B = 1.0f / 16384.0f;
constexpr float BN_EPS_C = 1e-5f;
constexpr int NUM_USERS_C = 1000000;

typedef __attribute__((ext_vector_type(8))) short bf16x8;
typedef __attribute__((ext_vector_type(4))) float f32x4;

__device__ inline unsigned short f2bf(float f) {
    union { float f; unsigned u; } v; v.f = f;
    unsigned r = v.u + 0x7FFFu + ((v.u >> 16) & 1u);   // RNE
    return (unsigned short)(r >> 16);
}
__device__ inline float bf2f(unsigned short h) {
    union { unsigned u; float f; } v; v.u = ((unsigned)h) << 16; return v.f;
}
__device__ inline bf16x8 pack8(float4 a, float4 b) {
    bf16x8 sv;
    sv[0] = (short)f2bf(a.x); sv[1] = (short)f2bf(a.y);
    sv[2] = (short)f2bf(a.z); sv[3] = (short)f2bf(a.w);
    sv[4] = (short)f2bf(b.x); sv[5] = (short)f2bf(b.y);
    sv[6] = (short)f2bf(b.z); sv[7] = (short)f2bf(b.w);
    return sv;
}
// XOR swizzles for pitch-256B / pitch-512B row-major bf16 tiles
__device__ inline unsigned swz256(int r, int kb) { return (unsigned)(r * 256 + (kb ^ ((r & 7) << 4))); }
__device__ inline unsigned swz512(int r, int kb) { return (unsigned)(r * 512 + (kb ^ ((r & 7) << 4))); }

// ---------------------------------------------------------------------------
// K0: one-time weight conversion f32 -> bf16 fragment-image layout, plus
//     zeroing of the stat replica buffers (8 replicas each now = 6144 f32).
// ---------------------------------------------------------------------------
__global__ __launch_bounds__(256) void wd_k0(
    const float* __restrict__ W1, const float* __restrict__ W2,
    unsigned short* __restrict__ img1, unsigned short* __restrict__ img2,
    float* __restrict__ stats)
{
    int t = blockIdx.x * 256 + threadIdx.x;        // grid 48*256 = 12288
    if (t < 6144) stats[t] = 0.f;                  // part1 (4096) + part2 (2048)
    if (t < 4096) {
        int a = t * 16, n = a >> 8, ks = a & 255;
        int k0 = (ks ^ ((n & 7) << 4)) >> 1;
        const float* src = W1 + (size_t)n * 128 + k0;
        float4 va = ((const float4*)src)[0];
        float4 vb = ((const float4*)src)[1];
        *(bf16x8*)((char*)img1 + a) = pack8(va, vb);
    } else if (t < 8192) {
        int tt = t - 4096;
        int a = tt * 16, h = a >> 15, rem = a & 32767, n = rem >> 8, ks = rem & 255;
        int kb = ks ^ ((n & 7) << 4);
        int k0 = h * 128 + (kb >> 1);
        const float* src = W2 + (size_t)n * 256 + k0;
        float4 va = ((const float4*)src)[0];
        float4 vb = ((const float4*)src)[1];
        *(bf16x8*)((char*)img2 + a) = pack8(va, vb);
    }
}

// ---------------------------------------------------------------------------
// K1: 512 blocks x 32 rows. X-gather + wide-gather issued first (HBM random,
//     longest latency); B-fragments + bias preloaded under that latency.
//     GEMM, +b1, ReLU -> h1s image; wide -> wideB; stats -> part1[8 reps].
// ---------------------------------------------------------------------------
__global__ __launch_bounds__(512, 4) void wd_k1(
    const int* __restrict__ ui, const int* __restrict__ ii,
    const float* __restrict__ utab, const float* __restrict__ itab,
    const float* __restrict__ wide_w,
    const unsigned short* __restrict__ img1, const float* __restrict__ b1,
    unsigned short* __restrict__ h1s, float* __restrict__ wideB,
    float* __restrict__ part1)
{
    __shared__ char Xs[8192];        // 32 x 256B, swizzled
    __shared__ char Bnc[16384];      // bounce: 32 x 512B, swizzled
    __shared__ float sstat[512];

    const int tid = threadIdx.x, bid = blockIdx.x, row0 = bid * 32;
    const int w = tid >> 6, lane = tid & 63, lr = lane & 15, lk = lane >> 4;

    // issue X-gather loads first (random HBM ~900cy)
    const int grow = tid >> 4, gkc = tid & 15;
    const float* gsrc = (gkc < 8)
        ? utab + (size_t)ui[row0 + grow] * 64 + gkc * 8
        : itab + (size_t)ii[row0 + grow] * 64 + (gkc - 8) * 8;
    float4 gva = ((const float4*)gsrc)[0];
    float4 gvb = ((const float4*)gsrc)[1];

    // wide-path gather rides the same latency window (tid<32)
    float wide_r = 0.f;
    if (tid < 32)
        wide_r = wide_w[ui[row0 + tid]] + wide_w[NUM_USERS_C + ii[row0 + tid]];

    // preload B fragments for this wave's 32 columns (bf16 image, L2-hot)
    bf16x8 bfr[2][4];
    float bias_r[2];
#pragma unroll
    for (int nj = 0; nj < 2; ++nj) {
        int n = w * 32 + nj * 16 + lr;
        bias_r[nj] = b1[n];
        const char* bp = (const char*)img1 + n * 256;
        int sx = (n & 7) << 4;
#pragma unroll
        for (int kst = 0; kst < 4; ++kst)
            bfr[nj][kst] = *(const bf16x8*)(bp + ((kst * 64 + lk * 16) ^ sx));
    }

    // write gathered X to LDS
    *(bf16x8*)(Xs + swz256(grow, gkc * 16)) = pack8(gva, gvb);
    __syncthreads();

    f32x4 acc[2][2];
#pragma unroll
    for (int mi = 0; mi < 2; ++mi)
#pragma unroll
        for (int nj = 0; nj < 2; ++nj) acc[mi][nj] = (f32x4){0.f, 0.f, 0.f, 0.f};

#pragma unroll
    for (int kst = 0; kst < 4; ++kst) {
        int kb = kst * 64 + lk * 16;
        bf16x8 a0 = *(const bf16x8*)(Xs + swz256(lr, kb));
        bf16x8 a1v = *(const bf16x8*)(Xs + swz256(16 + lr, kb));
#pragma unroll
        for (int nj = 0; nj < 2; ++nj) {
            acc[0][nj] = __builtin_amdgcn_mfma_f32_16x16x32_bf16(a0, bfr[nj][kst], acc[0][nj], 0, 0, 0);
            acc[1][nj] = __builtin_amdgcn_mfma_f32_16x16x32_bf16(a1v, bfr[nj][kst], acc[1][nj], 0, 0, 0);
        }
    }

    // epilogue: bias + relu + bf16, bounce to Bnc, per-col stats
#pragma unroll
    for (int nj = 0; nj < 2; ++nj) {
        int col = w * 32 + nj * 16 + lr;
        float s = 0.f, q = 0.f;
#pragma unroll
        for (int mi = 0; mi < 2; ++mi)
#pragma unroll
            for (int reg = 0; reg < 4; ++reg) {
                int rl = mi * 16 + lk * 4 + reg;
                float v = fmaxf(acc[mi][nj][reg] + bias_r[nj], 0.f);
                unsigned short hb = f2bf(v);
                float vr = bf2f(hb);
                s += vr; q += vr * vr;
                *(unsigned short*)(Bnc + swz512(rl, col * 2)) = hb;
            }
        s += __shfl_xor(s, 16); s += __shfl_xor(s, 32);
        q += __shfl_xor(q, 16); q += __shfl_xor(q, 32);
        if (lk == 0) { sstat[col] = s; sstat[256 + col] = q; }   // unique writer per col
    }
    __syncthreads();

    // dump 16 KB tile (32B per thread, coalesced) + wide store + stats replica add
    {
        const char* s0 = Bnc + tid * 32;
        char* d0 = (char*)h1s + (size_t)bid * 16384 + tid * 32;
        *(bf16x8*)d0 = *(const bf16x8*)s0;
        *(bf16x8*)(d0 + 16) = *(const bf16x8*)(s0 + 16);
    }
    if (tid < 32) wideB[row0 + tid] = wide_r;
    atomicAdd(&part1[(size_t)(bid & 7) * 512 + tid], sstat[tid]);
}

// ---------------------------------------------------------------------------
// K2: 512 blocks x 32 rows. T14 split: raw h1 tile loads issued to registers
//     FIRST, BN coeffs + B-preload + bias computed under that latency, then
//     transform + ds_write after the barrier. GEMM -> +b2, ReLU -> h2s image;
//     stats -> part2[8 reps].
// ---------------------------------------------------------------------------
__global__ __launch_bounds__(512, 4) void wd_k2(
    const unsigned short* __restrict__ h1s, const float* __restrict__ part1,
    const float* __restrict__ g1, const float* __restrict__ be1,
    const unsigned short* __restrict__ img2, const float* __restrict__ b2,
    unsigned short* __restrict__ h2s, float* __restrict__ part2)
{
    __shared__ char As[16384];       // 32 x 512B, swizzled (h1 image layout)
    __shared__ char Bnc[8192];       // bounce: 32 x 256B, swizzled
    __shared__ float a1s[256], c1s[256], sstat[256];

    const int tid = threadIdx.x, bid = blockIdx.x;
    const int w = tid >> 6, lane = tid & 63, lr = lane & 15, lk = lane >> 4;
    const int n = w * 16 + lr;            // this lane's output column (0..127)
    const int sx = (n & 7) << 4;

    // (1) issue raw A-tile loads to registers (L2/L3 latency starts now)
    bf16x8 hv0 = *(const bf16x8*)((const char*)h1s + (size_t)bid * 16384 + tid * 16);
    bf16x8 hv1 = *(const bf16x8*)((const char*)h1s + (size_t)bid * 16384 + 8192 + tid * 16);

    // (2) preload B fragments from img2 (L2-hot) + bias
    const float bias = b2[n];
    bf16x8 bfr[8];
#pragma unroll
    for (int h = 0; h < 2; ++h)
#pragma unroll
        for (int kst = 0; kst < 4; ++kst)
            bfr[h * 4 + kst] = *(const bf16x8*)((const char*)img2 + h * 32768 + n * 256 + ((kst * 64 + lk * 16) ^ sx));

    // (3) BN1 coefficients from 8 replicas
    if (tid < 256) {
        float s = 0.f, q = 0.f;
#pragma unroll
        for (int r = 0; r < 8; ++r) { s += part1[r * 512 + tid]; q += part1[r * 512 + 256 + tid]; }
        float mu = s * INV_B;
        float var = fmaf(q, INV_B, -mu * mu);
        float rs = rsqrtf(var + BN_EPS_C);
        float a = g1[tid] * rs;
        a1s[tid] = a;
        c1s[tid] = fmaf(-mu, a, be1[tid]);
    }
    __syncthreads();

    // (4) transform + write A tile (value transform, layout preserved)
#pragma unroll
    for (int it = 0; it < 2; ++it) {
        int a = it * 8192 + tid * 16;
        int r = a >> 9, ks = a & 511;
        int k0 = (ks ^ ((r & 7) << 4)) >> 1;
        bf16x8 hv = it ? hv1 : hv0;
        bf16x8 sv;
#pragma unroll
        for (int j = 0; j < 8; ++j) {
            float f = bf2f((unsigned short)hv[j]);
            f = fmaf(a1s[k0 + j], f, c1s[k0 + j]);
            sv[j] = (short)f2bf(f);
        }
        *(bf16x8*)(As + a) = sv;
    }
    __syncthreads();

    f32x4 acc[2];
    acc[0] = (f32x4){0.f, 0.f, 0.f, 0.f};
    acc[1] = (f32x4){0.f, 0.f, 0.f, 0.f};
#pragma unroll
    for (int k8 = 0; k8 < 8; ++k8) {
        int kb = (k8 * 64 + lk * 16) ^ ((lr & 7) << 4);   // (16+lr)&7 == lr&7
        bf16x8 a0 = *(const bf16x8*)(As + lr * 512 + kb);
        bf16x8 a1v = *(const bf16x8*)(As + (16 + lr) * 512 + kb);
        acc[0] = __builtin_amdgcn_mfma_f32_16x16x32_bf16(a0, bfr[k8], acc[0], 0, 0, 0);
        acc[1] = __builtin_amdgcn_mfma_f32_16x16x32_bf16(a1v, bfr[k8], acc[1], 0, 0, 0);
    }

    // epilogue
    {
        float s = 0.f, q = 0.f;
#pragma unroll
        for (int mi = 0; mi < 2; ++mi)
#pragma unroll
            for (int reg = 0; reg < 4; ++reg) {
                int rl = mi * 16 + lk * 4 + reg;
                float v = fmaxf(acc[mi][reg] + bias, 0.f);
                unsigned short hb = f2bf(v);
                float vr = bf2f(hb);
                s += vr; q += vr * vr;
                *(unsigned short*)(Bnc + swz256(rl, n * 2)) = hb;
            }
        s += __shfl_xor(s, 16); s += __shfl_xor(s, 32);
        q += __shfl_xor(q, 16); q += __shfl_xor(q, 32);
        if (lk == 0) { sstat[n] = s; sstat[128 + n] = q; }
    }
    __syncthreads();

    // dump 8 KB tile + stats replica add
    *(bf16x8*)((char*)h2s + (size_t)bid * 8192 + tid * 16) = *(const bf16x8*)(Bnc + tid * 16);
    if (tid < 256) atomicAdd(&part2[(size_t)(bid & 7) * 256 + tid], sstat[tid]);
}

// ---------------------------------------------------------------------------
// K3: BN2 folded into W3; per-row dot on h2s image (swizzle-aware reads)
//     + precomputed wide + sigmoid. 512 blocks x 32 rows.
// ---------------------------------------------------------------------------
__global__ __launch_bounds__(128, 4) void wd_k3(
    const float* __restrict__ wideB, const float* __restrict__ wide_b,
    const unsigned short* __restrict__ h2s, const float* __restrict__ part2,
    const float* __restrict__ g2, const float* __restrict__ be2,
    const float* __restrict__ W3, const float* __restrict__ b3,
    float* __restrict__ out)
{
    __shared__ float af[128], cf[128];
    const int tid = threadIdx.x, bid = blockIdx.x;
    const int r = tid >> 2, kq = tid & 3;
    const int row = bid * 32 + r;

    float wide = 0.f;
    if (kq == 0) wide = wideB[row];

    {
        float s = 0.f, q = 0.f;
#pragma unroll
        for (int rr = 0; rr < 8; ++rr) { s += part2[rr * 256 + tid]; q += part2[rr * 256 + 128 + tid]; }
        float mu = s * INV_B;
        float var = fmaf(q, INV_B, -mu * mu);
        float rs = rsqrtf(var + BN_EPS_C);
        float a = g2[tid] * rs;
        float c = fmaf(-mu, a, be2[tid]);
        float w3 = W3[tid];
        af[tid] = a * w3;
        cf[tid] = c * w3;
    }
    __syncthreads();

    const char* tb = (const char*)h2s + (size_t)bid * 8192 + r * 256;
    float acc = 0.f;
#pragma unroll
    for (int j = 0; j < 4; ++j) {
        int ks = (kq * 64 + j * 16) ^ ((r & 7) << 4);
        bf16x8 hv = *(const bf16x8*)(tb + ks);
#pragma unroll
        for (int e = 0; e < 8; ++e) {
            float h = bf2f((unsigned short)hv[e]);
            int k = kq * 32 + j * 8 + e;
            acc += fmaf(h, af[k], cf[k]);
        }
    }
    acc += __shfl_xor(acc, 1);
    acc += __shfl_xor(acc, 2);
    if (kq == 0) {
        float logit = acc + b3[0] + wide_b[0] + wide;
        out[row] = 1.f / (1.f + expf(-logit));
    }
}

extern "C" void kernel_launch(void* const* d_in, const int* in_sizes, int n_in,
                              void* d_out, int out_size, void* d_ws, size_t ws_size,
                              hipStream_t stream)
{
    const int*   ui     = (const int*)d_in[0];
    const int*   ii     = (const int*)d_in[1];
    const float* wide_w = (const float*)d_in[2];
    const float* wide_b = (const float*)d_in[3];
    const float* utab   = (const float*)d_in[4];
    const float* itab   = (const float*)d_in[5];
    const float* W1     = (const float*)d_in[6];
    const float* b1     = (const float*)d_in[7];
    const float* g1     = (const float*)d_in[8];
    const float* be1    = (const float*)d_in[9];
    const float* W2     = (const float*)d_in[10];
    const float* b2     = (const float*)d_in[11];
    const float* g2     = (const float*)d_in[12];
    const float* be2    = (const float*)d_in[13];
    const float* W3     = (const float*)d_in[14];
    const float* b3     = (const float*)d_in[15];
    float* outp = (float*)d_out;

    char* base = (char*)d_ws;
    float* part1 = (float*)base;                                   // 8*512 f32 = 16 KB
    float* part2 = (float*)(base + 16384);                         // 8*256 f32 = 8 KB
    unsigned short* img1 = (unsigned short*)(base + 49152);        // 64 KB
    unsigned short* img2 = (unsigned short*)(base + 49152 + 65536);
    float* wideB = (float*)(base + 49152 + 131072);                // 64 KB
    unsigned short* h1s  = (unsigned short*)(base + 49152 + 131072 + 65536);      // 8 MB
    unsigned short* h2s  = (unsigned short*)(base + 49152 + 131072 + 65536 + (size_t)512 * 16384);

    wd_k0<<<48, 256, 0, stream>>>(W1, W2, img1, img2, part1);
    wd_k1<<<512, 512, 0, stream>>>(ui, ii, utab, itab, wide_w, img1, b1, h1s, wideB, part1);
    wd_k2<<<512, 512, 0, stream>>>(h1s, part1, g1, be1, img2, b2, h2s, part2);
    wd_k3<<<512, 128, 0, stream>>>(wideB, wide_b, h2s, part2, g2, be2, W3, b3, outp);
}